// Round 1
// baseline (307.192 us; speedup 1.0000x reference)
//
#include <hip/hip_runtime.h>
#include <stdint.h>

// Problem constants
#define B_   4
#define T_   2048
#define D_   512
#define H_   8
#define HS_  64
#define M1   (B_*T_)      // 8192 rows
#define NQKV 1536         // q|k|v stacked output columns

typedef __attribute__((ext_vector_type(8))) short bf16x8;
typedef __attribute__((ext_vector_type(4))) float f32x4;

__device__ __forceinline__ unsigned short f2bf(float f) {
  union { float f; unsigned u; } v; v.f = f;
  unsigned r = v.u + 0x7fffu + ((v.u >> 16) & 1u);   // RNE
  return (unsigned short)(r >> 16);
}

__device__ __forceinline__ void gload_lds16(const void* g, void* l) {
  __builtin_amdgcn_global_load_lds(
      (const __attribute__((address_space(1))) void*)g,
      (__attribute__((address_space(3))) void*)l,
      16, 0, 0);
}

// ---------------- prep kernels ----------------
__global__ __launch_bounds__(256) void k_cast_x(const float* __restrict__ x,
                                                unsigned short* __restrict__ xb) {
  int i = blockIdx.x * 256 + threadIdx.x;            // 4 floats per thread
  float4 v = ((const float4*)x)[i];
  ushort4 o;
  o.x = f2bf(v.x); o.y = f2bf(v.y); o.z = f2bf(v.z); o.w = f2bf(v.w);
  ((ushort4*)xb)[i] = o;
}

// Wt[n][d], n in [0,1536): proj=n>>9, h=(n>>6)&7, e=n&63 ; Wt[n][d] = Wproj[h][d][e]
__global__ __launch_bounds__(256) void k_prep_wqkv(const float* __restrict__ Wq,
                                                   const float* __restrict__ Wk,
                                                   const float* __restrict__ Wv,
                                                   unsigned short* __restrict__ Wt) {
  int idx = blockIdx.x * 256 + threadIdx.x;          // < 1536*512
  int n = idx >> 9, d = idx & 511;
  int proj = n >> 9, c = n & 511, h = c >> 6, e = c & 63;
  const float* W = (proj == 0) ? Wq : ((proj == 1) ? Wk : Wv);
  Wt[idx] = f2bf(W[((h << 9) + d) * 64 + e]);
}

// Wot[n][d] = Wo[d][n]
__global__ __launch_bounds__(256) void k_prep_wo(const float* __restrict__ Wo,
                                                 unsigned short* __restrict__ Wt) {
  int idx = blockIdx.x * 256 + threadIdx.x;          // < 512*512
  int n = idx >> 9, d = idx & 511;
  Wt[idx] = f2bf(Wo[(d << 9) + n]);
}

// ---------------- GEMM: C[M][N] = A[M][512] * Bt[N][512]^T ----------------
// MODE 0: scatter bf16 into Qb [B,H,T,64], Kb [B,H,T,64], Vt [B,H,64,T]
// MODE 1: fp32 out + bias into Cout [M][512]
template<int MODE>
__global__ __launch_bounds__(256) void k_gemm(
    const unsigned short* __restrict__ A, const unsigned short* __restrict__ Bt,
    unsigned short* __restrict__ Qb, unsigned short* __restrict__ Kb,
    unsigned short* __restrict__ Vt,
    const float* __restrict__ bo, float* __restrict__ Cout)
{
  const int m0 = blockIdx.y * 128, n0 = blockIdx.x * 128;
  __shared__ unsigned short At[128 * 32];
  __shared__ unsigned short Bs[128 * 32];
  const int tid = threadIdx.x, lane = tid & 63, wid = tid >> 6;
  const int wm = wid >> 1, wn = wid & 1;
  const int r16 = lane & 15, g = lane >> 4;

  f32x4 acc[4][4];
  const f32x4 fz = {0.f, 0.f, 0.f, 0.f};
#pragma unroll
  for (int i = 0; i < 4; ++i)
#pragma unroll
    for (int j = 0; j < 4; ++j) acc[i][j] = fz;

  for (int k0 = 0; k0 < 512; k0 += 32) {
#pragma unroll
    for (int j = 0; j < 2; ++j) {
      const int idx = j * 256 + tid;
      const int rr = idx >> 2, cc = (idx & 3) << 3;
      gload_lds16(A + (size_t)(m0 + rr) * 512 + k0 + cc, &At[(j * 256 + wid * 64) * 8]);
      gload_lds16(Bt + (size_t)(n0 + rr) * 512 + k0 + cc, &Bs[(j * 256 + wid * 64) * 8]);
    }
    __syncthreads();
    bf16x8 am[4], bn[4];
#pragma unroll
    for (int mi = 0; mi < 4; ++mi)
      am[mi] = *(const bf16x8*)&At[(wm * 64 + mi * 16 + r16) * 32 + g * 8];
#pragma unroll
    for (int ni = 0; ni < 4; ++ni)
      bn[ni] = *(const bf16x8*)&Bs[(wn * 64 + ni * 16 + r16) * 32 + g * 8];
#pragma unroll
    for (int mi = 0; mi < 4; ++mi)
#pragma unroll
      for (int ni = 0; ni < 4; ++ni)
        acc[mi][ni] = __builtin_amdgcn_mfma_f32_16x16x32_bf16(am[mi], bn[ni], acc[mi][ni], 0, 0, 0);
    __syncthreads();
  }

#pragma unroll
  for (int mi = 0; mi < 4; ++mi) {
#pragma unroll
    for (int ni = 0; ni < 4; ++ni) {
#pragma unroll
      for (int r = 0; r < 4; ++r) {
        const int m = m0 + wm * 64 + mi * 16 + g * 4 + r;
        const int n = n0 + wn * 64 + ni * 16 + r16;
        const float val = acc[mi][ni][r];
        if (MODE == 0) {
          const int proj = n >> 9, c = n & 511, h = c >> 6, e = c & 63;
          const int b = m >> 11, t = m & 2047;
          const unsigned short bv = f2bf(val);
          if (proj == 0)      Qb[(((size_t)(b * 8 + h) * 2048 + t) << 6) + e] = bv;
          else if (proj == 1) Kb[(((size_t)(b * 8 + h) * 2048 + t) << 6) + e] = bv;
          else                Vt[(((size_t)(b * 8 + h) << 6) + e) * 2048 + t] = bv;
        } else {
          Cout[(size_t)m * 512 + n] = val + bo[n];
        }
      }
    }
  }
}

// ---------------- flash attention ----------------
// grid (T/64, B*H), block 256. Each wave: 16 q-rows; KVBLK=32.
__global__ __launch_bounds__(256) void k_attn(
    const unsigned short* __restrict__ Qb, const unsigned short* __restrict__ Kb,
    const unsigned short* __restrict__ Vt, unsigned short* __restrict__ Ob)
{
  const int bh = blockIdx.y;
  const int b = bh >> 3, h = bh & 7;
  const int tid = threadIdx.x, lane = tid & 63, wid = tid >> 6;
  const int q0 = blockIdx.x * 64 + wid * 16;
  const int r16 = lane & 15, g = lane >> 4;
  const unsigned short* Qh = Qb + (size_t)bh * T_ * 64;
  const unsigned short* Kh = Kb + (size_t)bh * T_ * 64;
  const unsigned short* Vh = Vt + (size_t)bh * 64 * T_;

  __shared__ unsigned short Plds[4][16 * 40];        // stride 40 shorts = 80B (conflict-light)
  unsigned short* myP = &Plds[wid][0];

  const bf16x8 qa0 = *(const bf16x8*)&Qh[(size_t)(q0 + r16) * 64 + g * 8];
  const bf16x8 qa1 = *(const bf16x8*)&Qh[(size_t)(q0 + r16) * 64 + 32 + g * 8];

  const f32x4 fz = {0.f, 0.f, 0.f, 0.f};
  f32x4 acc[4];
#pragma unroll
  for (int eb = 0; eb < 4; ++eb) acc[eb] = fz;
  float M[4], L[4];
#pragma unroll
  for (int r = 0; r < 4; ++r) { M[r] = -1e30f; L[r] = 0.0f; }
  const float SC = 0.125f * 1.44269504f;             // HS^-0.5 * log2(e)

  for (int kv0 = 0; kv0 < T_; kv0 += 32) {
    const bf16x8 k00 = *(const bf16x8*)&Kh[(size_t)(kv0 + r16) * 64 + g * 8];
    const bf16x8 k01 = *(const bf16x8*)&Kh[(size_t)(kv0 + r16) * 64 + 32 + g * 8];
    const bf16x8 k10 = *(const bf16x8*)&Kh[(size_t)(kv0 + 16 + r16) * 64 + g * 8];
    const bf16x8 k11 = *(const bf16x8*)&Kh[(size_t)(kv0 + 16 + r16) * 64 + 32 + g * 8];
    f32x4 s0 = fz, s1 = fz;
    s0 = __builtin_amdgcn_mfma_f32_16x16x32_bf16(qa0, k00, s0, 0, 0, 0);
    s0 = __builtin_amdgcn_mfma_f32_16x16x32_bf16(qa1, k01, s0, 0, 0, 0);
    s1 = __builtin_amdgcn_mfma_f32_16x16x32_bf16(qa0, k10, s1, 0, 0, 0);
    s1 = __builtin_amdgcn_mfma_f32_16x16x32_bf16(qa1, k11, s1, 0, 0, 0);

    float v0[4], v1[4], rmax[4];
#pragma unroll
    for (int r = 0; r < 4; ++r) {
      v0[r] = s0[r] * SC; v1[r] = s1[r] * SC;
      rmax[r] = fmaxf(v0[r], v1[r]);
    }
#pragma unroll
    for (int off = 1; off < 16; off <<= 1)
#pragma unroll
      for (int r = 0; r < 4; ++r)
        rmax[r] = fmaxf(rmax[r], __shfl_xor(rmax[r], off));

    float p0[4], p1[4], rs[4];
#pragma unroll
    for (int r = 0; r < 4; ++r) {
      const float mn = fmaxf(M[r], rmax[r]);
      const float al = exp2f(M[r] - mn);
      M[r] = mn;
      p0[r] = exp2f(v0[r] - mn);
      p1[r] = exp2f(v1[r] - mn);
      rs[r] = p0[r] + p1[r];
      L[r] *= al;
#pragma unroll
      for (int eb = 0; eb < 4; ++eb) acc[eb][r] *= al;
    }
#pragma unroll
    for (int off = 1; off < 16; off <<= 1)
#pragma unroll
      for (int r = 0; r < 4; ++r)
        rs[r] += __shfl_xor(rs[r], off);
#pragma unroll
    for (int r = 0; r < 4; ++r) L[r] += rs[r];

    // P (16x32) -> LDS in row-major, re-read as MFMA A-fragment
#pragma unroll
    for (int r = 0; r < 4; ++r) {
      const int mrow = g * 4 + r;
      myP[mrow * 40 + r16]      = f2bf(p0[r]);
      myP[mrow * 40 + 16 + r16] = f2bf(p1[r]);
    }
    asm volatile("" ::: "memory");
    const bf16x8 pa = *(const bf16x8*)&myP[r16 * 40 + g * 8];
#pragma unroll
    for (int eb = 0; eb < 4; ++eb) {
      const bf16x8 vb = *(const bf16x8*)&Vh[(size_t)(eb * 16 + r16) * T_ + kv0 + g * 8];
      acc[eb] = __builtin_amdgcn_mfma_f32_16x16x32_bf16(pa, vb, acc[eb], 0, 0, 0);
    }
    asm volatile("" ::: "memory");
  }

  const size_t ob = (size_t)b * T_ * 512;
#pragma unroll
  for (int eb = 0; eb < 4; ++eb)
#pragma unroll
    for (int r = 0; r < 4; ++r) {
      const int t = q0 + g * 4 + r;
      Ob[ob + (size_t)t * 512 + h * 64 + eb * 16 + r16] = f2bf(acc[eb][r] / L[r]);
    }
}

// ---------------- launch ----------------
extern "C" void kernel_launch(void* const* d_in, const int* in_sizes, int n_in,
                              void* d_out, int out_size, void* d_ws, size_t ws_size,
                              hipStream_t stream) {
  const float* x  = (const float*)d_in[0];
  const float* Wq = (const float*)d_in[1];
  const float* Wk = (const float*)d_in[2];
  const float* Wv = (const float*)d_in[3];
  const float* Wo = (const float*)d_in[4];
  const float* bo = (const float*)d_in[5];
  float* out = (float*)d_out;
  char* ws = (char*)d_ws;

  unsigned short* xb  = (unsigned short*)(ws);                 // 8192*512*2   = 8 MiB
  unsigned short* Wtq = (unsigned short*)(ws + 8388608);       // 1536*512*2
  unsigned short* Wto = (unsigned short*)(ws + 9961472);       // 512*512*2
  unsigned short* Qb  = (unsigned short*)(ws + 10485760);      // 8 MiB
  unsigned short* Kb  = (unsigned short*)(ws + 18874368);      // 8 MiB
  unsigned short* Vt  = (unsigned short*)(ws + 27262976);      // 8 MiB
  unsigned short* Ob  = (unsigned short*)(ws + 35651584);      // 8 MiB

  k_cast_x  <<<4096, 256, 0, stream>>>(x, xb);
  k_prep_wqkv<<<3072, 256, 0, stream>>>(Wq, Wk, Wv, Wtq);
  k_prep_wo <<<1024, 256, 0, stream>>>(Wo, Wto);
  k_gemm<0> <<<dim3(12, 64), 256, 0, stream>>>(xb, Wtq, Qb, Kb, Vt, nullptr, nullptr);
  k_attn    <<<dim3(32, 32), 256, 0, stream>>>(Qb, Kb, Vt, Ob);
  k_gemm<1> <<<dim3(4, 64), 256, 0, stream>>>(Ob, Wto, nullptr, nullptr, nullptr, bo, out);
}

// Round 2
// 288.359 us; speedup vs baseline: 1.0653x; 1.0653x over previous
//
#include <hip/hip_runtime.h>
#include <stdint.h>

// Problem constants
#define B_   4
#define T_   2048
#define D_   512
#define H_   8
#define HS_  64
#define M1   (B_*T_)      // 8192 rows
#define NQKV 1536         // q|k|v stacked output columns

typedef __attribute__((ext_vector_type(8))) short bf16x8;
typedef __attribute__((ext_vector_type(4))) float f32x4;

__device__ __forceinline__ unsigned short f2bf(float f) {
  union { float f; unsigned u; } v; v.f = f;
  unsigned r = v.u + 0x7fffu + ((v.u >> 16) & 1u);   // RNE
  return (unsigned short)(r >> 16);
}

__device__ __forceinline__ void gload_lds16(const void* g, void* l) {
  __builtin_amdgcn_global_load_lds(
      (const __attribute__((address_space(1))) void*)g,
      (__attribute__((address_space(3))) void*)l,
      16, 0, 0);
}

// ---------------- prep kernels ----------------
__global__ __launch_bounds__(256) void k_cast_x(const float* __restrict__ x,
                                                unsigned short* __restrict__ xb) {
  int i = blockIdx.x * 256 + threadIdx.x;            // 4 floats per thread
  float4 v = ((const float4*)x)[i];
  ushort4 o;
  o.x = f2bf(v.x); o.y = f2bf(v.y); o.z = f2bf(v.z); o.w = f2bf(v.w);
  ((ushort4*)xb)[i] = o;
}

// Wt[n][d], n in [0,1536): proj=n>>9, h=(n>>6)&7, e=n&63 ; Wt[n][d] = Wproj[h][d][e]
__global__ __launch_bounds__(256) void k_prep_wqkv(const float* __restrict__ Wq,
                                                   const float* __restrict__ Wk,
                                                   const float* __restrict__ Wv,
                                                   unsigned short* __restrict__ Wt) {
  int idx = blockIdx.x * 256 + threadIdx.x;          // < 1536*512
  int n = idx >> 9, d = idx & 511;
  int proj = n >> 9, c = n & 511, h = c >> 6, e = c & 63;
  const float* W = (proj == 0) ? Wq : ((proj == 1) ? Wk : Wv);
  Wt[idx] = f2bf(W[((h << 9) + d) * 64 + e]);
}

// Wot[n][d] = Wo[d][n]
__global__ __launch_bounds__(256) void k_prep_wo(const float* __restrict__ Wo,
                                                 unsigned short* __restrict__ Wt) {
  int idx = blockIdx.x * 256 + threadIdx.x;          // < 512*512
  int n = idx >> 9, d = idx & 511;
  Wt[idx] = f2bf(Wo[(d << 9) + n]);
}

// ---------------- GEMM: C[M][N] = A[M][512] * Bt[N][512]^T ----------------
// MODE 0: scatter bf16 into Qb [B,H,T,64] (pre-scaled by HS^-0.5*log2e),
//         Kb [B,H,T,64], Vp [B,H,64,T] with k-permutation within 32-blocks
// MODE 1: fp32 out + bias into Cout [M][512]
template<int MODE>
__global__ __launch_bounds__(256) void k_gemm(
    const unsigned short* __restrict__ A, const unsigned short* __restrict__ Bt,
    unsigned short* __restrict__ Qb, unsigned short* __restrict__ Kb,
    unsigned short* __restrict__ Vp,
    const float* __restrict__ bo, float* __restrict__ Cout)
{
  const int m0 = blockIdx.y * 128, n0 = blockIdx.x * 128;
  __shared__ unsigned short At[128 * 32];
  __shared__ unsigned short Bs[128 * 32];
  const int tid = threadIdx.x, lane = tid & 63, wid = tid >> 6;
  const int wm = wid >> 1, wn = wid & 1;
  const int r16 = lane & 15, g = lane >> 4;

  f32x4 acc[4][4];
  const f32x4 fz = {0.f, 0.f, 0.f, 0.f};
#pragma unroll
  for (int i = 0; i < 4; ++i)
#pragma unroll
    for (int j = 0; j < 4; ++j) acc[i][j] = fz;

  for (int k0 = 0; k0 < 512; k0 += 32) {
#pragma unroll
    for (int j = 0; j < 2; ++j) {
      const int idx = j * 256 + tid;
      const int rr = idx >> 2, cc = (idx & 3) << 3;
      gload_lds16(A + (size_t)(m0 + rr) * 512 + k0 + cc, &At[(j * 256 + wid * 64) * 8]);
      gload_lds16(Bt + (size_t)(n0 + rr) * 512 + k0 + cc, &Bs[(j * 256 + wid * 64) * 8]);
    }
    __syncthreads();
    bf16x8 am[4], bn[4];
#pragma unroll
    for (int mi = 0; mi < 4; ++mi)
      am[mi] = *(const bf16x8*)&At[(wm * 64 + mi * 16 + r16) * 32 + g * 8];
#pragma unroll
    for (int ni = 0; ni < 4; ++ni)
      bn[ni] = *(const bf16x8*)&Bs[(wn * 64 + ni * 16 + r16) * 32 + g * 8];
#pragma unroll
    for (int mi = 0; mi < 4; ++mi)
#pragma unroll
      for (int ni = 0; ni < 4; ++ni)
        acc[mi][ni] = __builtin_amdgcn_mfma_f32_16x16x32_bf16(am[mi], bn[ni], acc[mi][ni], 0, 0, 0);
    __syncthreads();
  }

  const float QSC = 0.18033688f;                     // HS^-0.5 * log2(e)
#pragma unroll
  for (int mi = 0; mi < 4; ++mi) {
#pragma unroll
    for (int ni = 0; ni < 4; ++ni) {
#pragma unroll
      for (int r = 0; r < 4; ++r) {
        const int m = m0 + wm * 64 + mi * 16 + g * 4 + r;
        const int n = n0 + wn * 64 + ni * 16 + r16;
        const float val = acc[mi][ni][r];
        if (MODE == 0) {
          const int proj = n >> 9, c = n & 511, h = c >> 6, e = c & 63;
          const int b = m >> 11, t = m & 2047;
          if (proj == 0) {
            Qb[(((size_t)(b * 8 + h) * 2048 + t) << 6) + e] = f2bf(val * QSC);
          } else if (proj == 1) {
            Kb[(((size_t)(b * 8 + h) * 2048 + t) << 6) + e] = f2bf(val);
          } else {
            // k-permuted within each 32-block so PV's A(V^T)/B(P) k-slots align:
            // kk -> j = ((kk>>2)&3)*8 + (kk>>4)*4 + (kk&3)
            const int kk = t & 31, tblk = t >> 5;
            const int j = (((kk >> 2) & 3) << 3) + ((kk >> 4) << 2) + (kk & 3);
            Vp[(((size_t)(b * 8 + h) << 6) + e) * 2048 + (tblk << 5) + j] = f2bf(val);
          }
        } else {
          Cout[(size_t)m * 512 + n] = val + bo[n];
        }
      }
    }
  }
}

// ---------------- flash attention (swapped QK^T, in-register softmax) ----------------
// grid (T/64, B*H), block 256 = 4 independent waves, each owning 16 q-rows.
// Per 32-kv tile: S^T = mfma(K,Q) so lane holds q=lane&15 and 8 k-scores.
__global__ __launch_bounds__(256) void k_attn(
    const unsigned short* __restrict__ Qb, const unsigned short* __restrict__ Kb,
    const unsigned short* __restrict__ Vp, unsigned short* __restrict__ Ob)
{
  const int bh = blockIdx.y;
  const int b = bh >> 3, h = bh & 7;
  const int tid = threadIdx.x, lane = tid & 63, wid = tid >> 6;
  const int q0 = blockIdx.x * 64 + wid * 16;
  const int r16 = lane & 15, g = lane >> 4;
  const unsigned short* Qh = Qb + (size_t)bh * T_ * 64;
  const unsigned short* Kh = Kb + (size_t)bh * T_ * 64;
  const unsigned short* Vh = Vp + (size_t)bh * 64 * T_;

  // Q as MFMA B-frag: col = lane&15 = q-row, d = g*8+i  (Q pre-scaled)
  const bf16x8 qa0 = *(const bf16x8*)&Qh[(size_t)(q0 + r16) * 64 + g * 8];
  const bf16x8 qa1 = *(const bf16x8*)&Qh[(size_t)(q0 + r16) * 64 + 32 + g * 8];

  const f32x4 fz = {0.f, 0.f, 0.f, 0.f};
  f32x4 acc[4];                                      // O^T: q=lane&15, e=eb*16+g*4+r
#pragma unroll
  for (int eb = 0; eb < 4; ++eb) acc[eb] = fz;
  float M = -1e30f, L = 0.0f;

  for (int kv0 = 0; kv0 < T_; kv0 += 32) {
    // K as MFMA A-frag: row = lane&15 = k within tile, d = g*8+i
    const bf16x8 k00 = *(const bf16x8*)&Kh[(size_t)(kv0 + r16) * 64 + g * 8];
    const bf16x8 k01 = *(const bf16x8*)&Kh[(size_t)(kv0 + r16) * 64 + 32 + g * 8];
    const bf16x8 k10 = *(const bf16x8*)&Kh[(size_t)(kv0 + 16 + r16) * 64 + g * 8];
    const bf16x8 k11 = *(const bf16x8*)&Kh[(size_t)(kv0 + 16 + r16) * 64 + 32 + g * 8];
    f32x4 s0 = __builtin_amdgcn_mfma_f32_16x16x32_bf16(k00, qa0, fz, 0, 0, 0);
    s0 = __builtin_amdgcn_mfma_f32_16x16x32_bf16(k01, qa1, s0, 0, 0, 0);
    f32x4 s1 = __builtin_amdgcn_mfma_f32_16x16x32_bf16(k10, qa0, fz, 0, 0, 0);
    s1 = __builtin_amdgcn_mfma_f32_16x16x32_bf16(k11, qa1, s1, 0, 0, 0);
    // lane now holds S^T for its q-row: s0[r] -> k=kv0+g*4+r, s1[r] -> k=kv0+16+g*4+r

    float rmax = fmaxf(fmaxf(fmaxf(s0[0], s0[1]), fmaxf(s0[2], s0[3])),
                       fmaxf(fmaxf(s1[0], s1[1]), fmaxf(s1[2], s1[3])));
    rmax = fmaxf(rmax, __shfl_xor(rmax, 16));
    rmax = fmaxf(rmax, __shfl_xor(rmax, 32));

    const float mn = fmaxf(M, rmax);
    const float al = exp2f(M - mn);
    M = mn;
    float p[8];
#pragma unroll
    for (int r = 0; r < 4; ++r) {
      p[r]     = exp2f(s0[r] - mn);
      p[4 + r] = exp2f(s1[r] - mn);
    }
    float rs = ((p[0] + p[1]) + (p[2] + p[3])) + ((p[4] + p[5]) + (p[6] + p[7]));
    rs += __shfl_xor(rs, 16);
    rs += __shfl_xor(rs, 32);
    L = L * al + rs;

    bf16x8 pa;
#pragma unroll
    for (int i = 0; i < 8; ++i) pa[i] = (short)f2bf(p[i]);

#pragma unroll
    for (int eb = 0; eb < 4; ++eb) {
#pragma unroll
      for (int r = 0; r < 4; ++r) acc[eb][r] *= al;
    }
#pragma unroll
    for (int eb = 0; eb < 4; ++eb) {
      const bf16x8 vb = *(const bf16x8*)&Vh[(size_t)(eb * 16 + r16) * T_ + kv0 + g * 8];
      acc[eb] = __builtin_amdgcn_mfma_f32_16x16x32_bf16(vb, pa, acc[eb], 0, 0, 0);
    }
  }

  const float invL = 1.0f / L;
  const size_t ob = (size_t)b * T_ * 512;
  const int t = q0 + r16;
#pragma unroll
  for (int eb = 0; eb < 4; ++eb)
#pragma unroll
    for (int r = 0; r < 4; ++r) {
      Ob[ob + (size_t)t * 512 + h * 64 + eb * 16 + g * 4 + r] = f2bf(acc[eb][r] * invL);
    }
}

// ---------------- launch ----------------
extern "C" void kernel_launch(void* const* d_in, const int* in_sizes, int n_in,
                              void* d_out, int out_size, void* d_ws, size_t ws_size,
                              hipStream_t stream) {
  const float* x  = (const float*)d_in[0];
  const float* Wq = (const float*)d_in[1];
  const float* Wk = (const float*)d_in[2];
  const float* Wv = (const float*)d_in[3];
  const float* Wo = (const float*)d_in[4];
  const float* bo = (const float*)d_in[5];
  float* out = (float*)d_out;
  char* ws = (char*)d_ws;

  unsigned short* xb  = (unsigned short*)(ws);                 // 8192*512*2   = 8 MiB
  unsigned short* Wtq = (unsigned short*)(ws + 8388608);       // 1536*512*2
  unsigned short* Wto = (unsigned short*)(ws + 9961472);       // 512*512*2
  unsigned short* Qb  = (unsigned short*)(ws + 10485760);      // 8 MiB
  unsigned short* Kb  = (unsigned short*)(ws + 18874368);      // 8 MiB
  unsigned short* Vp  = (unsigned short*)(ws + 27262976);      // 8 MiB
  unsigned short* Ob  = (unsigned short*)(ws + 35651584);      // 8 MiB

  k_cast_x  <<<4096, 256, 0, stream>>>(x, xb);
  k_prep_wqkv<<<3072, 256, 0, stream>>>(Wq, Wk, Wv, Wtq);
  k_prep_wo <<<1024, 256, 0, stream>>>(Wo, Wto);
  k_gemm<0> <<<dim3(12, 64), 256, 0, stream>>>(xb, Wtq, Qb, Kb, Vp, nullptr, nullptr);
  k_attn    <<<dim3(32, 32), 256, 0, stream>>>(Qb, Kb, Vp, Ob);
  k_gemm<1> <<<dim3(4, 64), 256, 0, stream>>>(Ob, Wto, nullptr, nullptr, nullptr, bo, out);
}